// Round 3
// baseline (2663.999 us; speedup 1.0000x reference)
//
#include <hip/hip_runtime.h>

#define N_PTS 8192
#define NSAMP 1024
#define NGRP  32

// ---------------------------------------------------------------------------
// Kernel 1: farthest point sampling. One block (1024 threads) per batch.
// Each thread owns 8 consecutive points in registers (coords + running dist).
// Distance rounding matches XLA:CPU's scan-compiled contracted reduce:
//   d = fma(dz,dz, fma(dy,dy, dx*dx))
// argmax ties -> lowest index (first occurrence).  DO NOT TOUCH — bit-exact.
// ---------------------------------------------------------------------------
__global__ __launch_bounds__(1024) void fps_kernel(
    const float* __restrict__ xyz, float* __restrict__ out_sampled)
{
  #pragma clang fp contract(off)
  const int b = blockIdx.x;
  const int t = threadIdx.x;
  const float* bx = xyz + (size_t)b * N_PTS * 3;

  float px[8], py[8], pz[8], dist[8];
  {
    const float4* src = (const float4*)(bx + t * 24);
    float4 v0 = src[0], v1 = src[1], v2 = src[2], v3 = src[3], v4 = src[4], v5 = src[5];
    px[0]=v0.x; py[0]=v0.y; pz[0]=v0.z;
    px[1]=v0.w; py[1]=v1.x; pz[1]=v1.y;
    px[2]=v1.z; py[2]=v1.w; pz[2]=v2.x;
    px[3]=v2.y; py[3]=v2.z; pz[3]=v2.w;
    px[4]=v3.x; py[4]=v3.y; pz[4]=v3.z;
    px[5]=v3.w; py[5]=v4.x; pz[5]=v4.y;
    px[6]=v4.z; py[6]=v4.w; pz[6]=v5.x;
    px[7]=v5.y; py[7]=v5.z; pz[7]=v5.w;
  }
  #pragma unroll
  for (int r = 0; r < 8; ++r) dist[r] = 10000000000.0f;

  __shared__ float red_v[16];
  __shared__ int   red_i[16];
  __shared__ float sc[3];
  __shared__ int   s_far;
  if (t == 0) {
    s_far = 0;
    sc[0] = px[0]; sc[1] = py[0]; sc[2] = pz[0];  // initial centroid = point 0
  }
  __syncthreads();

  const int lane = t & 63;
  const int wv   = t >> 6;

  for (int it = 0; it < NSAMP; ++it) {
    float cx = sc[0], cy = sc[1], cz = sc[2];
    if (t == 0) {
      float* o = out_sampled + ((size_t)b * NSAMP + it) * 3;
      o[0] = cx; o[1] = cy; o[2] = cz;
    }

    float bv = -1.0f;
    #pragma unroll
    for (int r = 0; r < 8; ++r) {
      float dx = px[r] - cx;
      float dy = py[r] - cy;
      float dz = pz[r] - cz;
      // scan-compiled contracted reduce: fma(dz,dz, fma(dy,dy, dx*dx))
      float d  = fmaf(dz, dz, fmaf(dy, dy, dx * dx));
      float nd = fminf(dist[r], d);
      dist[r] = nd;
      bv = fmaxf(bv, nd);
    }
    // lowest local index whose (updated) dist equals the thread max
    int bi = t * 8 + 7;
    #pragma unroll
    for (int r = 6; r >= 0; --r) bi = (dist[r] == bv) ? (t * 8 + r) : bi;

    // wave butterfly: max value, min index on exact ties
    #pragma unroll
    for (int off = 32; off > 0; off >>= 1) {
      float ov = __shfl_xor(bv, off, 64);
      int   oi = __shfl_xor(bi, off, 64);
      if (ov > bv || (ov == bv && oi < bi)) { bv = ov; bi = oi; }
    }
    if (lane == 0) { red_v[wv] = bv; red_i[wv] = bi; }
    __syncthreads();                       // A: partials visible

    if (t < 64) {
      float v2 = (t < 16) ? red_v[t] : -1.0f;
      int   i2 = (t < 16) ? red_i[t] : 0x7fffffff;
      #pragma unroll
      for (int off = 8; off > 0; off >>= 1) {
        float ov = __shfl_xor(v2, off, 64);
        int   oi = __shfl_xor(i2, off, 64);
        if (ov > v2 || (ov == v2 && oi < i2)) { v2 = ov; i2 = oi; }
      }
      if (t == 0) s_far = i2;
    }
    __syncthreads();                       // B: winner index visible

    int f = s_far;
    if ((f >> 3) == t) {                   // owner publishes exact coords
      int r = f & 7;
      float ox = px[0], oy = py[0], oz = pz[0];
      #pragma unroll
      for (int q = 1; q < 8; ++q) {
        if (r == q) { ox = px[q]; oy = py[q]; oz = pz[q]; }
      }
      sc[0] = ox; sc[1] = oy; sc[2] = oz;
    }
    __syncthreads();                       // C: centroid visible
  }
}

// ---------------------------------------------------------------------------
// Kernel 2: query_ball_point. One wave per centroid, ballot-prefix append in
// ascending index order, early exit once 32 found.
// query_ball_point runs EAGERLY in the reference (op-by-op XLA kernels), so
// the rounding is MIXED:
//   na/nb: squares rounded individually, then plain adds (reduce kernel,
//          nothing to contract):  ((x*x) + (y*y)) + (z*z)
//   dot:   Eigen gemm (einsum) -> fma chain ascending k:
//          fma(z,cz, fma(y,cy, x*cx))
//   sq = (na + nb) - 2*dot   (x2 exact; contraction-neutral)
// Self-point: nb==na bitwise -> sq = 2(na-dot) ~ +-3e-8, never > R2. Included.
// ---------------------------------------------------------------------------
__global__ __launch_bounds__(256) void ball_kernel(
    const float* __restrict__ xyz, const float* __restrict__ sampled,
    int* __restrict__ gidx)
{
  #pragma clang fp contract(off)
  const float R2 = (float)(0.2 * 0.2);
  int gt = blockIdx.x * 256 + threadIdx.x;
  int w = gt >> 6;                // centroid id, 0..16383
  int lane = gt & 63;
  const int b = w >> 10;
  const float* cp = sampled + (size_t)w * 3;
  float cx = cp[0], cy = cp[1], cz = cp[2];
  float na = ((cx * cx) + (cy * cy)) + (cz * cz);   // eager: plain adds
  const float* bx = xyz + (size_t)b * N_PTS * 3;
  int* out = gidx + (size_t)w * NGRP;

  int cnt = 0;
  int first = 0;
  for (int base = 0; base < N_PTS && cnt < NGRP; base += 64) {
    int p = base + lane;
    float x = bx[p * 3 + 0];
    float y = bx[p * 3 + 1];
    float z = bx[p * 3 + 2];
    float nb  = ((x * x) + (y * y)) + (z * z);      // eager: plain adds
    float dot = fmaf(cz, z, fmaf(cy, y, cx * x));   // Eigen fma chain
    float sq  = (na + nb) - (2.0f * dot);
    bool inr = !(sq > R2);
    unsigned long long m = __ballot(inr);
    if (cnt == 0 && m != 0ull) first = base + (__ffsll(m) - 1);
    int before = __popcll(m & ((1ull << lane) - 1ull));
    int pos = cnt + before;
    if (inr && pos < NGRP) out[pos] = p;
    cnt += __popcll(m);
  }
  if (cnt < NGRP) {
    int q = cnt + lane;
    if (q < NGRP) out[q] = first;   // pad with first in-radius index
  }
}

// ---------------------------------------------------------------------------
// Kernel 3: gather + MLP(67->64->128->256, relu) + max over 32 points.
// One 256-thread block per centroid. Transposed LDS tiles [c][k] (stride 36)
// so inner k-loops are aligned float4 broadcast reads; c-outer register
// blocking; max-pool folded into layer-3 accumulators.
// ---------------------------------------------------------------------------
__global__ __launch_bounds__(256) void mlp_kernel(
    const float* __restrict__ xyz, const float* __restrict__ fea,
    const float* __restrict__ sampled, const int* __restrict__ gidx,
    const float* __restrict__ W1, const float* __restrict__ b1,
    const float* __restrict__ W2, const float* __restrict__ b2,
    const float* __restrict__ W3, const float* __restrict__ b3,
    float* __restrict__ out)
{
  __shared__ float fT[67][36];     // feats^T  [c][k]
  __shared__ float h1T[64][36];    // h1^T     [c][k]
  __shared__ float h2T[128][36];   // h2^T     [c][k]
  __shared__ int   sidx[32];
  __shared__ float sc[4];

  const int bs = blockIdx.x;        // b*1024 + s
  const int b  = bs >> 10;
  const int t  = threadIdx.x;

  if (t < 32) sidx[t] = gidx[(size_t)bs * 32 + t];
  if (t < 3)  sc[t] = sampled[(size_t)bs * 3 + t];
  __syncthreads();

  // gather: rel(3) ++ fea(64) -> fT[c][k]
  {
    const int k = t >> 3, c0 = t & 7;
    const int p = sidx[k];
    const float* xp = xyz + ((size_t)b * N_PTS + p) * 3;
    const float* fp = fea + ((size_t)b * N_PTS + p) * 64;
    for (int c = c0; c < 67; c += 8) {
      float v = (c < 3) ? (xp[c] - sc[c]) : fp[c - 3];
      fT[c][k] = v;
    }
  }
  __syncthreads();

  // layer 1: 64 outputs x 32 points
  {
    const int j = t & 63, g = t >> 6;     // k = g*8 .. g*8+7
    float acc[8];
    float bb = b1[j];
    #pragma unroll
    for (int r = 0; r < 8; ++r) acc[r] = bb;
    for (int c = 0; c < 67; ++c) {
      float w = W1[c * 64 + j];
      const float4* hp = (const float4*)&fT[c][g * 8];
      float4 f0 = hp[0], f1 = hp[1];
      acc[0] = fmaf(f0.x, w, acc[0]);
      acc[1] = fmaf(f0.y, w, acc[1]);
      acc[2] = fmaf(f0.z, w, acc[2]);
      acc[3] = fmaf(f0.w, w, acc[3]);
      acc[4] = fmaf(f1.x, w, acc[4]);
      acc[5] = fmaf(f1.y, w, acc[5]);
      acc[6] = fmaf(f1.z, w, acc[6]);
      acc[7] = fmaf(f1.w, w, acc[7]);
    }
    float* dst = &h1T[j][g * 8];
    #pragma unroll
    for (int r = 0; r < 8; ++r) dst[r] = fmaxf(acc[r], 0.0f);
  }
  __syncthreads();

  // layer 2: 128 outputs x 32 points
  {
    const int j = t & 127, g = t >> 7;    // k = g*16 .. g*16+15
    float acc[16];
    float bb = b2[j];
    #pragma unroll
    for (int r = 0; r < 16; ++r) acc[r] = bb;
    for (int c = 0; c < 64; ++c) {
      float w = W2[c * 128 + j];
      const float4* hp = (const float4*)&h1T[c][g * 16];
      #pragma unroll
      for (int q = 0; q < 4; ++q) {
        float4 f = hp[q];
        acc[q * 4 + 0] = fmaf(f.x, w, acc[q * 4 + 0]);
        acc[q * 4 + 1] = fmaf(f.y, w, acc[q * 4 + 1]);
        acc[q * 4 + 2] = fmaf(f.z, w, acc[q * 4 + 2]);
        acc[q * 4 + 3] = fmaf(f.w, w, acc[q * 4 + 3]);
      }
    }
    float* dst = &h2T[j][g * 16];
    #pragma unroll
    for (int r = 0; r < 16; ++r) dst[r] = fmaxf(acc[r], 0.0f);
  }
  __syncthreads();

  // layer 3 + max-pool: 256 outputs, all 32 points per thread
  {
    const int j = t;
    float acc[32];
    float bb = b3[j];
    #pragma unroll
    for (int r = 0; r < 32; ++r) acc[r] = bb;
    for (int c = 0; c < 128; ++c) {
      float w = W3[c * 256 + j];
      const float4* hp = (const float4*)&h2T[c][0];
      #pragma unroll
      for (int q = 0; q < 8; ++q) {
        float4 f = hp[q];
        acc[q * 4 + 0] = fmaf(f.x, w, acc[q * 4 + 0]);
        acc[q * 4 + 1] = fmaf(f.y, w, acc[q * 4 + 1]);
        acc[q * 4 + 2] = fmaf(f.z, w, acc[q * 4 + 2]);
        acc[q * 4 + 3] = fmaf(f.w, w, acc[q * 4 + 3]);
      }
    }
    float m = acc[0];
    #pragma unroll
    for (int r = 1; r < 32; ++r) m = fmaxf(m, acc[r]);
    m = fmaxf(m, 0.0f);                    // max_k relu(x_k) = relu(max_k x_k)
    out[(size_t)bs * 256 + j] = m;
  }
}

// ---------------------------------------------------------------------------
extern "C" void kernel_launch(void* const* d_in, const int* in_sizes, int n_in,
                              void* d_out, int out_size, void* d_ws, size_t ws_size,
                              hipStream_t stream) {
  const float* xyz = (const float*)d_in[0];
  const float* fea = (const float*)d_in[1];
  const float* W1  = (const float*)d_in[2];
  const float* b1  = (const float*)d_in[3];
  const float* W2  = (const float*)d_in[4];
  const float* b2  = (const float*)d_in[5];
  const float* W3  = (const float*)d_in[6];
  const float* b3  = (const float*)d_in[7];

  float* outp    = (float*)d_out;
  float* sampled = outp;                    // output 0: (16,1024,3)
  float* mlp_out = outp + 16 * 1024 * 3;    // output 1: (16,1024,256)
  int*   gidx    = (int*)d_ws;              // 16384*32 ints = 2 MB scratch

  fps_kernel<<<16, 1024, 0, stream>>>(xyz, sampled);
  ball_kernel<<<4096, 256, 0, stream>>>(xyz, sampled, gidx);
  mlp_kernel<<<16384, 256, 0, stream>>>(xyz, fea, sampled, gidx,
                                        W1, b1, W2, b2, W3, b3, mlp_out);
}

// Round 4
// 1754.928 us; speedup vs baseline: 1.5180x; 1.5180x over previous
//
#include <hip/hip_runtime.h>

#define N_PTS 8192
#define NSAMP 1024
#define NGRP  32

// ---------------------------------------------------------------------------
// Kernel 1: farthest point sampling. One block of 512 threads (8 waves) per
// batch; each thread owns 16 consecutive points in registers.
// Distance rounding matches XLA:CPU's scan-compiled contracted reduce:
//   d = fma(dz,dz, fma(dy,dy, dx*dx))          (bit-exact, DO NOT TOUCH)
// argmax ties -> lowest index (first occurrence).
//
// Per-iteration protocol (ONE barrier):
//   - update dists in regs, thread-local (max, lowest-idx)
//   - per-wave value-only shuffle butterfly -> wave max v*
//   - ballot(bv==v*) -> lowest lane (lane order == index order) -> wave index
//   - lane0 writes (v*, idx) to ping-pong partial slot; __syncthreads
//   - EVERY thread scans the 8 partials (strict > keeps lowest wave = lowest
//     index) -> winner f; broadcast global load of xyz[f] = next centroid
//   - t0 appends centroid to a 12KB LDS ring; flushed coalesced at the end
// No global stores inside the loop => no vmcnt drain at the barrier.
// ---------------------------------------------------------------------------
__global__ __launch_bounds__(512) void fps_kernel(
    const float* __restrict__ xyz, float* __restrict__ out_sampled)
{
  #pragma clang fp contract(off)
  const int b = blockIdx.x;
  const int t = threadIdx.x;
  const float* bx = xyz + (size_t)b * N_PTS * 3;

  // load 16 points (48 floats) as 12 float4
  float px[16], py[16], pz[16], dist[16];
  {
    float4 v[12];
    const float4* src = (const float4*)(bx + t * 48);
    #pragma unroll
    for (int q = 0; q < 12; ++q) v[q] = src[q];
    const float* f = (const float*)v;
    #pragma unroll
    for (int r = 0; r < 16; ++r) {
      px[r] = f[3 * r + 0];
      py[r] = f[3 * r + 1];
      pz[r] = f[3 * r + 2];
      dist[r] = 10000000000.0f;
    }
  }

  __shared__ uint2 part[2][8];          // ping-pong (value bits, index)
  __shared__ float out_lds[NSAMP * 3];  // centroid coords, flushed at end

  const int lane = t & 63;
  const int wv   = t >> 6;

  // initial centroid = point 0 (broadcast load)
  float cx = bx[0], cy = bx[1], cz = bx[2];

  for (int it = 0; it < NSAMP; ++it) {
    if (t == 0) {
      out_lds[it * 3 + 0] = cx;
      out_lds[it * 3 + 1] = cy;
      out_lds[it * 3 + 2] = cz;
    }

    // update distances; track thread-local max of UPDATED dists
    float bv = -1.0f;
    #pragma unroll
    for (int r = 0; r < 16; ++r) {
      float dx = px[r] - cx;
      float dy = py[r] - cy;
      float dz = pz[r] - cz;
      float d  = fmaf(dz, dz, fmaf(dy, dy, dx * dx));  // scan-fused rounding
      float nd = fminf(dist[r], d);
      dist[r] = nd;
      bv = fmaxf(bv, nd);
    }
    // lowest local index whose dist equals the thread max
    int bi = t * 16 + 15;
    #pragma unroll
    for (int r = 14; r >= 0; --r) bi = (dist[r] == bv) ? (t * 16 + r) : bi;

    // per-wave value-only butterfly max
    float vmax = bv;
    #pragma unroll
    for (int off = 32; off > 0; off >>= 1)
      vmax = fmaxf(vmax, __shfl_xor(vmax, off, 64));
    // lowest lane holding the max (lane order == index order)
    unsigned long long m = __ballot(bv == vmax);
    int L = __ffsll((long long)m) - 1;
    int widx = __shfl(bi, L, 64);

    const int slot = it & 1;
    if (lane == 0) part[slot][wv] = make_uint2(__float_as_uint(vmax), (unsigned)widx);
    __syncthreads();   // the ONLY barrier; ping-pong makes it WAR-safe

    // every thread scans the 8 partials (broadcast LDS reads, no conflicts)
    const uint4* pp = (const uint4*)&part[slot][0];
    uint4 p0 = pp[0], p1 = pp[1], p2 = pp[2], p3 = pp[3];
    float v = __uint_as_float(p0.x); unsigned f = p0.y;
    float w1v = __uint_as_float(p0.z);
    if (w1v > v) { v = w1v; f = p0.w; }
    float w2v = __uint_as_float(p1.x);
    if (w2v > v) { v = w2v; f = p1.y; }
    float w3v = __uint_as_float(p1.z);
    if (w3v > v) { v = w3v; f = p1.w; }
    float w4v = __uint_as_float(p2.x);
    if (w4v > v) { v = w4v; f = p2.y; }
    float w5v = __uint_as_float(p2.z);
    if (w5v > v) { v = w5v; f = p2.w; }
    float w6v = __uint_as_float(p3.x);
    if (w6v > v) { v = w6v; f = p3.y; }
    float w7v = __uint_as_float(p3.z);
    if (w7v > v) { v = w7v; f = p3.w; }

    // next centroid: broadcast load (single cache line, all lanes same addr)
    cx = bx[f * 3 + 0];
    cy = bx[f * 3 + 1];
    cz = bx[f * 3 + 2];
  }

  __syncthreads();
  // coalesced flush of centroids
  float* ob = out_sampled + (size_t)b * NSAMP * 3;
  #pragma unroll
  for (int i = t; i < NSAMP * 3; i += 512) ob[i] = out_lds[i];
}

// ---------------------------------------------------------------------------
// Kernel 2: query_ball_point. One wave per centroid, ballot-prefix append in
// ascending index order, early exit once 32 found.
// query_ball_point runs EAGERLY in the reference (op-by-op XLA kernels), so
// the rounding is MIXED (bit-exact, DO NOT TOUCH):
//   na/nb: squares rounded individually, then plain adds
//   dot:   Eigen gemm fma chain: fma(z,cz, fma(y,cy, x*cx))
//   sq = (na + nb) - 2*dot
// ---------------------------------------------------------------------------
__global__ __launch_bounds__(256) void ball_kernel(
    const float* __restrict__ xyz, const float* __restrict__ sampled,
    int* __restrict__ gidx)
{
  #pragma clang fp contract(off)
  const float R2 = (float)(0.2 * 0.2);
  int gt = blockIdx.x * 256 + threadIdx.x;
  int w = gt >> 6;                // centroid id, 0..16383
  int lane = gt & 63;
  const int b = w >> 10;
  const float* cp = sampled + (size_t)w * 3;
  float cx = cp[0], cy = cp[1], cz = cp[2];
  float na = ((cx * cx) + (cy * cy)) + (cz * cz);   // eager: plain adds
  const float* bx = xyz + (size_t)b * N_PTS * 3;
  int* out = gidx + (size_t)w * NGRP;

  int cnt = 0;
  int first = 0;
  for (int base = 0; base < N_PTS && cnt < NGRP; base += 64) {
    int p = base + lane;
    float x = bx[p * 3 + 0];
    float y = bx[p * 3 + 1];
    float z = bx[p * 3 + 2];
    float nb  = ((x * x) + (y * y)) + (z * z);      // eager: plain adds
    float dot = fmaf(cz, z, fmaf(cy, y, cx * x));   // Eigen fma chain
    float sq  = (na + nb) - (2.0f * dot);
    bool inr = !(sq > R2);
    unsigned long long m = __ballot(inr);
    if (cnt == 0 && m != 0ull) first = base + (__ffsll(m) - 1);
    int before = __popcll(m & ((1ull << lane) - 1ull));
    int pos = cnt + before;
    if (inr && pos < NGRP) out[pos] = p;
    cnt += __popcll(m);
  }
  if (cnt < NGRP) {
    int q = cnt + lane;
    if (q < NGRP) out[q] = first;   // pad with first in-radius index
  }
}

// ---------------------------------------------------------------------------
// Kernel 3: gather + MLP(67->64->128->256, relu) + max over 32 points.
// One 256-thread block per centroid. Transposed LDS tiles [c][k] (stride 36)
// so inner k-loops are aligned float4 broadcast reads; c-outer register
// blocking; max-pool folded into layer-3 accumulators.
// ---------------------------------------------------------------------------
__global__ __launch_bounds__(256) void mlp_kernel(
    const float* __restrict__ xyz, const float* __restrict__ fea,
    const float* __restrict__ sampled, const int* __restrict__ gidx,
    const float* __restrict__ W1, const float* __restrict__ b1,
    const float* __restrict__ W2, const float* __restrict__ b2,
    const float* __restrict__ W3, const float* __restrict__ b3,
    float* __restrict__ out)
{
  __shared__ float fT[67][36];     // feats^T  [c][k]
  __shared__ float h1T[64][36];    // h1^T     [c][k]
  __shared__ float h2T[128][36];   // h2^T     [c][k]
  __shared__ int   sidx[32];
  __shared__ float sc[4];

  const int bs = blockIdx.x;        // b*1024 + s
  const int b  = bs >> 10;
  const int t  = threadIdx.x;

  if (t < 32) sidx[t] = gidx[(size_t)bs * 32 + t];
  if (t < 3)  sc[t] = sampled[(size_t)bs * 3 + t];
  __syncthreads();

  // gather: rel(3) ++ fea(64) -> fT[c][k]
  {
    const int k = t >> 3, c0 = t & 7;
    const int p = sidx[k];
    const float* xp = xyz + ((size_t)b * N_PTS + p) * 3;
    const float* fp = fea + ((size_t)b * N_PTS + p) * 64;
    for (int c = c0; c < 67; c += 8) {
      float v = (c < 3) ? (xp[c] - sc[c]) : fp[c - 3];
      fT[c][k] = v;
    }
  }
  __syncthreads();

  // layer 1: 64 outputs x 32 points
  {
    const int j = t & 63, g = t >> 6;     // k = g*8 .. g*8+7
    float acc[8];
    float bb = b1[j];
    #pragma unroll
    for (int r = 0; r < 8; ++r) acc[r] = bb;
    for (int c = 0; c < 67; ++c) {
      float w = W1[c * 64 + j];
      const float4* hp = (const float4*)&fT[c][g * 8];
      float4 f0 = hp[0], f1 = hp[1];
      acc[0] = fmaf(f0.x, w, acc[0]);
      acc[1] = fmaf(f0.y, w, acc[1]);
      acc[2] = fmaf(f0.z, w, acc[2]);
      acc[3] = fmaf(f0.w, w, acc[3]);
      acc[4] = fmaf(f1.x, w, acc[4]);
      acc[5] = fmaf(f1.y, w, acc[5]);
      acc[6] = fmaf(f1.z, w, acc[6]);
      acc[7] = fmaf(f1.w, w, acc[7]);
    }
    float* dst = &h1T[j][g * 8];
    #pragma unroll
    for (int r = 0; r < 8; ++r) dst[r] = fmaxf(acc[r], 0.0f);
  }
  __syncthreads();

  // layer 2: 128 outputs x 32 points
  {
    const int j = t & 127, g = t >> 7;    // k = g*16 .. g*16+15
    float acc[16];
    float bb = b2[j];
    #pragma unroll
    for (int r = 0; r < 16; ++r) acc[r] = bb;
    for (int c = 0; c < 64; ++c) {
      float w = W2[c * 128 + j];
      const float4* hp = (const float4*)&h1T[c][g * 16];
      #pragma unroll
      for (int q = 0; q < 4; ++q) {
        float4 f = hp[q];
        acc[q * 4 + 0] = fmaf(f.x, w, acc[q * 4 + 0]);
        acc[q * 4 + 1] = fmaf(f.y, w, acc[q * 4 + 1]);
        acc[q * 4 + 2] = fmaf(f.z, w, acc[q * 4 + 2]);
        acc[q * 4 + 3] = fmaf(f.w, w, acc[q * 4 + 3]);
      }
    }
    float* dst = &h2T[j][g * 16];
    #pragma unroll
    for (int r = 0; r < 16; ++r) dst[r] = fmaxf(acc[r], 0.0f);
  }
  __syncthreads();

  // layer 3 + max-pool: 256 outputs, all 32 points per thread
  {
    const int j = t;
    float acc[32];
    float bb = b3[j];
    #pragma unroll
    for (int r = 0; r < 32; ++r) acc[r] = bb;
    for (int c = 0; c < 128; ++c) {
      float w = W3[c * 256 + j];
      const float4* hp = (const float4*)&h2T[c][0];
      #pragma unroll
      for (int q = 0; q < 8; ++q) {
        float4 f = hp[q];
        acc[q * 4 + 0] = fmaf(f.x, w, acc[q * 4 + 0]);
        acc[q * 4 + 1] = fmaf(f.y, w, acc[q * 4 + 1]);
        acc[q * 4 + 2] = fmaf(f.z, w, acc[q * 4 + 2]);
        acc[q * 4 + 3] = fmaf(f.w, w, acc[q * 4 + 3]);
      }
    }
    float m = acc[0];
    #pragma unroll
    for (int r = 1; r < 32; ++r) m = fmaxf(m, acc[r]);
    m = fmaxf(m, 0.0f);                    // max_k relu(x_k) = relu(max_k x_k)
    out[(size_t)bs * 256 + j] = m;
  }
}

// ---------------------------------------------------------------------------
extern "C" void kernel_launch(void* const* d_in, const int* in_sizes, int n_in,
                              void* d_out, int out_size, void* d_ws, size_t ws_size,
                              hipStream_t stream) {
  const float* xyz = (const float*)d_in[0];
  const float* fea = (const float*)d_in[1];
  const float* W1  = (const float*)d_in[2];
  const float* b1  = (const float*)d_in[3];
  const float* W2  = (const float*)d_in[4];
  const float* b2  = (const float*)d_in[5];
  const float* W3  = (const float*)d_in[6];
  const float* b3  = (const float*)d_in[7];

  float* outp    = (float*)d_out;
  float* sampled = outp;                    // output 0: (16,1024,3)
  float* mlp_out = outp + 16 * 1024 * 3;    // output 1: (16,1024,256)
  int*   gidx    = (int*)d_ws;              // 16384*32 ints = 2 MB scratch

  fps_kernel<<<16, 512, 0, stream>>>(xyz, sampled);
  ball_kernel<<<4096, 256, 0, stream>>>(xyz, sampled, gidx);
  mlp_kernel<<<16384, 256, 0, stream>>>(xyz, fea, sampled, gidx,
                                        W1, b1, W2, b2, W3, b3, mlp_out);
}

// Round 5
// 1527.860 us; speedup vs baseline: 1.7436x; 1.1486x over previous
//
#include <hip/hip_runtime.h>

#define N_PTS 8192
#define NSAMP 1024
#define NGRP  32

// DPP move: returns src shifted per ctrl; invalid lanes keep 'old' (=x itself),
// which is the identity for max-reduction. ctrl/masks must be literals.
#define DPP_MAXSTEP(r, ctrl)                                                  \
  r = fmaxf(r, __int_as_float(__builtin_amdgcn_update_dpp(                    \
          __float_as_int(r), __float_as_int(r), (ctrl), 0xf, 0xf, false)))

// ---------------------------------------------------------------------------
// Kernel 1: farthest point sampling. One block of 512 threads (8 waves) per
// batch; each thread owns 16 consecutive points in PURE SSA registers
// (named float4s, no local array -> no scratch spill; r4 had VGPR=48 = spilled).
// Distance rounding matches XLA:CPU's scan-compiled contracted reduce:
//   d = fma(dz,dz, fma(dy,dy, dx*dx))          (bit-exact, DO NOT TOUCH)
// argmax ties -> lowest index. Wave reduction via DPP v_max chain (6 deps,
// ~50cy) instead of ds_bpermute butterfly (~600cy); ballot picks lowest lane.
// ---------------------------------------------------------------------------
__global__ __launch_bounds__(512, 2) void fps_kernel(
    const float* __restrict__ xyz, float* __restrict__ out_sampled)
{
  #pragma clang fp contract(off)
  const int b = blockIdx.x;
  const int t = threadIdx.x;
  const float* bx = xyz + (size_t)b * N_PTS * 3;

  float px[16], py[16], pz[16], dist[16];
  {
    const float4* src = (const float4*)(bx + t * 48);
    float4 v0 = src[0], v1 = src[1], v2 = src[2];
    float4 v3 = src[3], v4 = src[4], v5 = src[5];
    float4 v6 = src[6], v7 = src[7], v8 = src[8];
    float4 v9 = src[9], v10 = src[10], v11 = src[11];
    px[ 0]=v0.x; py[ 0]=v0.y; pz[ 0]=v0.z;
    px[ 1]=v0.w; py[ 1]=v1.x; pz[ 1]=v1.y;
    px[ 2]=v1.z; py[ 2]=v1.w; pz[ 2]=v2.x;
    px[ 3]=v2.y; py[ 3]=v2.z; pz[ 3]=v2.w;
    px[ 4]=v3.x; py[ 4]=v3.y; pz[ 4]=v3.z;
    px[ 5]=v3.w; py[ 5]=v4.x; pz[ 5]=v4.y;
    px[ 6]=v4.z; py[ 6]=v4.w; pz[ 6]=v5.x;
    px[ 7]=v5.y; py[ 7]=v5.z; pz[ 7]=v5.w;
    px[ 8]=v6.x; py[ 8]=v6.y; pz[ 8]=v6.z;
    px[ 9]=v6.w; py[ 9]=v7.x; pz[ 9]=v7.y;
    px[10]=v7.z; py[10]=v7.w; pz[10]=v8.x;
    px[11]=v8.y; py[11]=v8.z; pz[11]=v8.w;
    px[12]=v9.x; py[12]=v9.y; pz[12]=v9.z;
    px[13]=v9.w; py[13]=v10.x; pz[13]=v10.y;
    px[14]=v10.z; py[14]=v10.w; pz[14]=v11.x;
    px[15]=v11.y; py[15]=v11.z; pz[15]=v11.w;
  }
  #pragma unroll
  for (int r = 0; r < 16; ++r) dist[r] = 10000000000.0f;

  __shared__ uint2 part[2][8];          // ping-pong (value bits, index)
  __shared__ float out_lds[NSAMP * 3];  // centroid coords, flushed at end

  const int lane = t & 63;
  const int wv   = t >> 6;

  float cx = bx[0], cy = bx[1], cz = bx[2];  // initial centroid = point 0

  for (int it = 0; it < NSAMP; ++it) {
    if (t == 0) {
      out_lds[it * 3 + 0] = cx;
      out_lds[it * 3 + 1] = cy;
      out_lds[it * 3 + 2] = cz;
    }

    // update distances; thread-local max of UPDATED dists
    float bv = -1.0f;
    #pragma unroll
    for (int r = 0; r < 16; ++r) {
      float dx = px[r] - cx;
      float dy = py[r] - cy;
      float dz = pz[r] - cz;
      float d  = fmaf(dz, dz, fmaf(dy, dy, dx * dx));  // scan-fused rounding
      float nd = fminf(dist[r], d);
      dist[r] = nd;
      bv = fmaxf(bv, nd);
    }
    // lowest local index whose dist equals the thread max
    int bi = t * 16 + 15;
    #pragma unroll
    for (int r = 14; r >= 0; --r) bi = (dist[r] == bv) ? (t * 16 + r) : bi;

    // wave-64 max via DPP chain; lane 63 holds the wave max
    float rmax = bv;
    DPP_MAXSTEP(rmax, 0x111);  // row_shr:1
    DPP_MAXSTEP(rmax, 0x112);  // row_shr:2
    DPP_MAXSTEP(rmax, 0x114);  // row_shr:4
    DPP_MAXSTEP(rmax, 0x118);  // row_shr:8
    DPP_MAXSTEP(rmax, 0x142);  // row_bcast:15
    DPP_MAXSTEP(rmax, 0x143);  // row_bcast:31
    float vmax = __int_as_float(
        __builtin_amdgcn_readlane(__float_as_int(rmax), 63));

    // lowest lane holding the max (lane order == index order)
    unsigned long long m = __ballot(bv == vmax);
    int L = __ffsll((long long)m) - 1;
    int widx = __builtin_amdgcn_readlane(bi, L);

    const int slot = it & 1;
    if (lane == 0) part[slot][wv] = make_uint2(__float_as_uint(vmax), (unsigned)widx);
    __syncthreads();   // the ONLY barrier; ping-pong makes it WAR-safe

    // every thread scans the 8 partials (broadcast LDS reads, no conflicts)
    const uint4* pp = (const uint4*)&part[slot][0];
    uint4 p0 = pp[0], p1 = pp[1], p2 = pp[2], p3 = pp[3];
    float v = __uint_as_float(p0.x); unsigned f = p0.y;
    float w1v = __uint_as_float(p0.z);
    if (w1v > v) { v = w1v; f = p0.w; }
    float w2v = __uint_as_float(p1.x);
    if (w2v > v) { v = w2v; f = p1.y; }
    float w3v = __uint_as_float(p1.z);
    if (w3v > v) { v = w3v; f = p1.w; }
    float w4v = __uint_as_float(p2.x);
    if (w4v > v) { v = w4v; f = p2.y; }
    float w5v = __uint_as_float(p2.z);
    if (w5v > v) { v = w5v; f = p2.w; }
    float w6v = __uint_as_float(p3.x);
    if (w6v > v) { v = w6v; f = p3.y; }
    float w7v = __uint_as_float(p3.z);
    if (w7v > v) { v = w7v; f = p3.w; }

    // next centroid: broadcast load (single cache line, all lanes same addr)
    cx = bx[f * 3 + 0];
    cy = bx[f * 3 + 1];
    cz = bx[f * 3 + 2];
  }

  __syncthreads();
  float* ob = out_sampled + (size_t)b * NSAMP * 3;
  for (int i = t; i < NSAMP * 3; i += 512) ob[i] = out_lds[i];
}

// ---------------------------------------------------------------------------
// Kernel 2: query_ball_point. One wave per centroid, ballot-prefix append in
// ascending index order, early exit once 32 found.
// EAGER reference rounding (bit-exact, DO NOT TOUCH):
//   na/nb: squares rounded individually, then plain adds
//   dot:   Eigen gemm fma chain: fma(z,cz, fma(y,cy, x*cx))
//   sq = (na + nb) - 2*dot
// ---------------------------------------------------------------------------
__global__ __launch_bounds__(256) void ball_kernel(
    const float* __restrict__ xyz, const float* __restrict__ sampled,
    int* __restrict__ gidx)
{
  #pragma clang fp contract(off)
  const float R2 = (float)(0.2 * 0.2);
  int gt = blockIdx.x * 256 + threadIdx.x;
  int w = gt >> 6;                // centroid id, 0..16383
  int lane = gt & 63;
  const int b = w >> 10;
  const float* cp = sampled + (size_t)w * 3;
  float cx = cp[0], cy = cp[1], cz = cp[2];
  float na = ((cx * cx) + (cy * cy)) + (cz * cz);   // eager: plain adds
  const float* bx = xyz + (size_t)b * N_PTS * 3;
  int* out = gidx + (size_t)w * NGRP;

  int cnt = 0;
  int first = 0;
  for (int base = 0; base < N_PTS && cnt < NGRP; base += 64) {
    int p = base + lane;
    float x = bx[p * 3 + 0];
    float y = bx[p * 3 + 1];
    float z = bx[p * 3 + 2];
    float nb  = ((x * x) + (y * y)) + (z * z);      // eager: plain adds
    float dot = fmaf(cz, z, fmaf(cy, y, cx * x));   // Eigen fma chain
    float sq  = (na + nb) - (2.0f * dot);
    bool inr = !(sq > R2);
    unsigned long long m = __ballot(inr);
    if (cnt == 0 && m != 0ull) first = base + (__ffsll(m) - 1);
    int before = __popcll(m & ((1ull << lane) - 1ull));
    int pos = cnt + before;
    if (inr && pos < NGRP) out[pos] = p;
    cnt += __popcll(m);
  }
  if (cnt < NGRP) {
    int q = cnt + lane;
    if (q < NGRP) out[q] = first;   // pad with first in-radius index
  }
}

// ---------------------------------------------------------------------------
// Kernel 3: gather + MLP(67->64->128->256, relu) + max over 32 points.
// One 256-thread block per centroid. Transposed LDS tiles [c][k] (stride 36,
// 16B-aligned rows). 2-way j-register-blocking: each thread computes TWO
// outputs, so each ds_read_b128 feeds 8 FMAs (was 4) -> halves LDS reads.
// Max-pool computed per k-half, combined via pmax LDS stage.
// ---------------------------------------------------------------------------
__global__ __launch_bounds__(256, 4) void mlp_kernel(
    const float* __restrict__ xyz, const float* __restrict__ fea,
    const float* __restrict__ sampled, const int* __restrict__ gidx,
    const float* __restrict__ W1, const float* __restrict__ b1,
    const float* __restrict__ W2, const float* __restrict__ b2,
    const float* __restrict__ W3, const float* __restrict__ b3,
    float* __restrict__ out)
{
  __shared__ float fT[67][36];     // feats^T  [c][k]
  __shared__ float h1T[64][36];    // h1^T     [c][k]
  __shared__ float h2T[128][36];   // h2^T     [c][k]
  __shared__ float pmax[2][256];   // layer-3 partial maxes per k-half
  __shared__ int   sidx[32];
  __shared__ float sc[4];

  const int bs = blockIdx.x;        // b*1024 + s
  const int b  = bs >> 10;
  const int t  = threadIdx.x;

  if (t < 32) sidx[t] = gidx[(size_t)bs * 32 + t];
  if (t < 3)  sc[t] = sampled[(size_t)bs * 3 + t];
  __syncthreads();

  // gather: rel(3) ++ fea(64) -> fT[c][k]
  {
    const int k = t >> 3, c0 = t & 7;
    const int p = sidx[k];
    const float* xp = xyz + ((size_t)b * N_PTS + p) * 3;
    const float* fp = fea + ((size_t)b * N_PTS + p) * 64;
    for (int c = c0; c < 67; c += 8) {
      float v = (c < 3) ? (xp[c] - sc[c]) : fp[c - 3];
      fT[c][k] = v;
    }
  }
  __syncthreads();

  // layer 1: outputs (j0, j0+32), 4 points each. j0 = t&31, kq = t>>5.
  {
    const int j0 = t & 31, kq = t >> 5;   // k = kq*4 .. kq*4+3
    float a0[4], a1[4];
    float bb0 = b1[j0], bb1 = b1[j0 + 32];
    #pragma unroll
    for (int r = 0; r < 4; ++r) { a0[r] = bb0; a1[r] = bb1; }
    for (int c = 0; c < 67; ++c) {
      float w0 = W1[c * 64 + j0];
      float w1 = W1[c * 64 + j0 + 32];
      float4 f = *(const float4*)&fT[c][kq * 4];
      a0[0] = fmaf(f.x, w0, a0[0]);  a1[0] = fmaf(f.x, w1, a1[0]);
      a0[1] = fmaf(f.y, w0, a0[1]);  a1[1] = fmaf(f.y, w1, a1[1]);
      a0[2] = fmaf(f.z, w0, a0[2]);  a1[2] = fmaf(f.z, w1, a1[2]);
      a0[3] = fmaf(f.w, w0, a0[3]);  a1[3] = fmaf(f.w, w1, a1[3]);
    }
    float* d0 = &h1T[j0][kq * 4];
    float* d1 = &h1T[j0 + 32][kq * 4];
    #pragma unroll
    for (int r = 0; r < 4; ++r) { d0[r] = fmaxf(a0[r], 0.0f); d1[r] = fmaxf(a1[r], 0.0f); }
  }
  __syncthreads();

  // layer 2: outputs (j0, j0+64), 8 points each. j0 = t&63, kh = t>>6.
  {
    const int j0 = t & 63, kh = t >> 6;   // k = kh*8 .. kh*8+7
    float a0[8], a1[8];
    float bb0 = b2[j0], bb1 = b2[j0 + 64];
    #pragma unroll
    for (int r = 0; r < 8; ++r) { a0[r] = bb0; a1[r] = bb1; }
    for (int c = 0; c < 64; ++c) {
      float w0 = W2[c * 128 + j0];
      float w1 = W2[c * 128 + j0 + 64];
      const float4* hp = (const float4*)&h1T[c][kh * 8];
      float4 f0 = hp[0], f1 = hp[1];
      a0[0] = fmaf(f0.x, w0, a0[0]);  a1[0] = fmaf(f0.x, w1, a1[0]);
      a0[1] = fmaf(f0.y, w0, a0[1]);  a1[1] = fmaf(f0.y, w1, a1[1]);
      a0[2] = fmaf(f0.z, w0, a0[2]);  a1[2] = fmaf(f0.z, w1, a1[2]);
      a0[3] = fmaf(f0.w, w0, a0[3]);  a1[3] = fmaf(f0.w, w1, a1[3]);
      a0[4] = fmaf(f1.x, w0, a0[4]);  a1[4] = fmaf(f1.x, w1, a1[4]);
      a0[5] = fmaf(f1.y, w0, a0[5]);  a1[5] = fmaf(f1.y, w1, a1[5]);
      a0[6] = fmaf(f1.z, w0, a0[6]);  a1[6] = fmaf(f1.z, w1, a1[6]);
      a0[7] = fmaf(f1.w, w0, a0[7]);  a1[7] = fmaf(f1.w, w1, a1[7]);
    }
    float* d0 = &h2T[j0][kh * 8];
    float* d1 = &h2T[j0 + 64][kh * 8];
    #pragma unroll
    for (int r = 0; r < 8; ++r) { d0[r] = fmaxf(a0[r], 0.0f); d1[r] = fmaxf(a1[r], 0.0f); }
  }
  __syncthreads();

  // layer 3 + max-pool: outputs (j0, j0+128), 16 points each. kh = t>>7.
  {
    const int j0 = t & 127, kh = t >> 7;  // k = kh*16 .. kh*16+15
    float a0[16], a1[16];
    float bb0 = b3[j0], bb1 = b3[j0 + 128];
    #pragma unroll
    for (int r = 0; r < 16; ++r) { a0[r] = bb0; a1[r] = bb1; }
    for (int c = 0; c < 128; ++c) {
      float w0 = W3[c * 256 + j0];
      float w1 = W3[c * 256 + j0 + 128];
      const float4* hp = (const float4*)&h2T[c][kh * 16];
      #pragma unroll
      for (int q = 0; q < 4; ++q) {
        float4 f = hp[q];
        a0[q*4+0] = fmaf(f.x, w0, a0[q*4+0]);  a1[q*4+0] = fmaf(f.x, w1, a1[q*4+0]);
        a0[q*4+1] = fmaf(f.y, w0, a0[q*4+1]);  a1[q*4+1] = fmaf(f.y, w1, a1[q*4+1]);
        a0[q*4+2] = fmaf(f.z, w0, a0[q*4+2]);  a1[q*4+2] = fmaf(f.z, w1, a1[q*4+2]);
        a0[q*4+3] = fmaf(f.w, w0, a0[q*4+3]);  a1[q*4+3] = fmaf(f.w, w1, a1[q*4+3]);
      }
    }
    float m0 = a0[0], m1 = a1[0];
    #pragma unroll
    for (int r = 1; r < 16; ++r) { m0 = fmaxf(m0, a0[r]); m1 = fmaxf(m1, a1[r]); }
    pmax[kh][j0]       = m0;
    pmax[kh][j0 + 128] = m1;
  }
  __syncthreads();

  {
    float v = fmaxf(pmax[0][t], pmax[1][t]);
    out[(size_t)bs * 256 + t] = fmaxf(v, 0.0f);   // relu(max) == max(relu)
  }
}

// ---------------------------------------------------------------------------
extern "C" void kernel_launch(void* const* d_in, const int* in_sizes, int n_in,
                              void* d_out, int out_size, void* d_ws, size_t ws_size,
                              hipStream_t stream) {
  const float* xyz = (const float*)d_in[0];
  const float* fea = (const float*)d_in[1];
  const float* W1  = (const float*)d_in[2];
  const float* b1  = (const float*)d_in[3];
  const float* W2  = (const float*)d_in[4];
  const float* b2  = (const float*)d_in[5];
  const float* W3  = (const float*)d_in[6];
  const float* b3  = (const float*)d_in[7];

  float* outp    = (float*)d_out;
  float* sampled = outp;                    // output 0: (16,1024,3)
  float* mlp_out = outp + 16 * 1024 * 3;    // output 1: (16,1024,256)
  int*   gidx    = (int*)d_ws;              // 16384*32 ints = 2 MB scratch

  fps_kernel<<<16, 512, 0, stream>>>(xyz, sampled);
  ball_kernel<<<4096, 256, 0, stream>>>(xyz, sampled, gidx);
  mlp_kernel<<<16384, 256, 0, stream>>>(xyz, fea, sampled, gidx,
                                        W1, b1, W2, b2, W3, b3, mlp_out);
}